// Round 1
// baseline (2704.457 us; speedup 1.0000x reference)
//
#include <hip/hip_runtime.h>

#define NN 100000
#define NE 1600000
#define DD 64

// ---------------- degree / normalization ----------------

__global__ __launch_bounds__(256) void k_count(const int* __restrict__ ei,
                                               int* __restrict__ deg) {
    int e = blockIdx.x * 256 + threadIdx.x;
    if (e < NE) atomicAdd(&deg[ei[NE + e]], 1);
}

__global__ __launch_bounds__(256) void k_dis(const int* __restrict__ deg,
                                             double* __restrict__ dis) {
    int i = blockIdx.x * 256 + threadIdx.x;
    if (i < NN) dis[i] = 1.0 / sqrt((double)(deg[i] + 1));  // +1 = self loop
}

// ---------------- h2 = in @ W  (64x64 W in LDS, f64 accumulate) ----------------

__global__ __launch_bounds__(256) void k_gemm(const float* __restrict__ in,
                                              const float* __restrict__ W,
                                              float* __restrict__ h2) {
    __shared__ float sW[DD * DD];
    __shared__ float sIn[4][DD];
    int t = threadIdx.x;
    for (int i = t; i < DD * DD; i += 256) sW[i] = W[i];
    int r = t >> 6, c = t & 63;
    int row = blockIdx.x * 4 + r;       // NN % 4 == 0, no bounds check needed
    sIn[r][c] = in[row * DD + c];
    __syncthreads();
    double acc = 0.0;
#pragma unroll
    for (int k = 0; k < DD; ++k) acc += (double)sIn[r][k] * (double)sW[k * DD + c];
    h2[row * DD + c] = (float)acc;
}

// ---------------- acc = self-loop term ----------------

__global__ __launch_bounds__(256) void k_self(const float* __restrict__ h2,
                                              const double* __restrict__ dis,
                                              double* __restrict__ acc) {
    int idx = blockIdx.x * 256 + threadIdx.x;   // < NN*DD
    int i = idx >> 6;
    double d = dis[i];
    acc[idx] = (double)h2[idx] * d * d;
}

// ---------------- edge scatter: one wave (64 lanes) per edge ----------------

__global__ __launch_bounds__(256) void k_edge(const int* __restrict__ ei,
                                              const float* __restrict__ h2,
                                              const double* __restrict__ dis,
                                              double* __restrict__ acc) {
    int gid = blockIdx.x * 256 + threadIdx.x;   // < NE*64 = 102.4M < 2^31
    int e = gid >> 6;
    int f = gid & 63;
    int s = ei[e];
    int d = ei[NE + e];
    double nrm = dis[s] * dis[d];
    double v = (double)h2[s * DD + f] * nrm;
    unsafeAtomicAdd(&acc[(size_t)d * DD + f], v);   // global_atomic_add_f64
}

// ---------------- out = (f32) maybe_elu(acc + b) ----------------

__global__ __launch_bounds__(256) void k_act(const double* __restrict__ acc,
                                             const float* __restrict__ b,
                                             float* __restrict__ out,
                                             int apply_elu) {
    int idx = blockIdx.x * 256 + threadIdx.x;   // < NN*DD
    int f = idx & 63;
    double v = acc[idx] + (double)b[f];
    if (apply_elu) v = (v > 0.0) ? v : expm1(v);
    out[idx] = (float)v;
}

// ---------------- launch ----------------

extern "C" void kernel_launch(void* const* d_in, const int* in_sizes, int n_in,
                              void* d_out, int out_size, void* d_ws, size_t ws_size,
                              hipStream_t stream) {
    const float* x  = (const float*)d_in[0];
    const int*   ei = (const int*)d_in[1];
    // d_in[2] = batch (unused)
    const float* W1 = (const float*)d_in[3];
    const float* b1 = (const float*)d_in[4];
    const float* W2 = (const float*)d_in[5];
    const float* b2 = (const float*)d_in[6];
    const float* W3 = (const float*)d_in[7];
    const float* b3 = (const float*)d_in[8];
    const float* W4 = (const float*)d_in[9];
    const float* b4 = (const float*)d_in[10];
    float* out = (float*)d_out;

    char* ws = (char*)d_ws;
    size_t off = 0;
    double* acc = (double*)(ws + off); off += (size_t)NN * DD * sizeof(double);  // 51.2 MB
    double* dis = (double*)(ws + off); off += (size_t)NN * sizeof(double);       //  0.8 MB
    int*    deg = (int*)   (ws + off); off += (size_t)NN * sizeof(int);          //  0.4 MB
    float*  h2  = (float*) (ws + off); off += (size_t)NN * DD * sizeof(float);   // 25.6 MB
    float*  A   = (float*) (ws + off); off += (size_t)NN * DD * sizeof(float);   // 25.6 MB
    // total ~103.6 MB of d_ws

    hipMemsetAsync(deg, 0, (size_t)NN * sizeof(int), stream);
    k_count<<<(NE + 255) / 256, 256, 0, stream>>>(ei, deg);
    k_dis<<<(NN + 255) / 256, 256, 0, stream>>>(deg, dis);

    struct Layer { const float* in; const float* W; const float* b; float* o; int elu; };
    Layer L[4] = {
        { x,   W1, b1, A,   1 },
        { A,   W2, b2, out, 1 },
        { out, W3, b3, A,   1 },
        { A,   W4, b4, out, 0 },
    };

    for (int l = 0; l < 4; ++l) {
        k_gemm<<<NN / 4, 256, 0, stream>>>(L[l].in, L[l].W, h2);
        k_self<<<NN * DD / 256, 256, 0, stream>>>(h2, dis, acc);
        k_edge<<<(NE * DD) / 256, 256, 0, stream>>>(ei, h2, dis, acc);
        k_act<<<NN * DD / 256, 256, 0, stream>>>(acc, L[l].b, L[l].o, L[l].elu);
    }
}

// Round 2
// 1039.909 us; speedup vs baseline: 2.6007x; 2.6007x over previous
//
#include <hip/hip_runtime.h>

#define NN 100000
#define NE 1600000
#define DD 64
#define NB 98           // ceil(NN/1024) scan blocks

// ---------------- degree / normalization ----------------

__global__ __launch_bounds__(256) void k_count(const int* __restrict__ ei,
                                               int* __restrict__ deg) {
    int e = blockIdx.x * 256 + threadIdx.x;
    if (e < NE) atomicAdd(&deg[ei[NE + e]], 1);
}

__global__ __launch_bounds__(256) void k_dis(const int* __restrict__ deg,
                                             double* __restrict__ dis) {
    int i = blockIdx.x * 256 + threadIdx.x;
    if (i < NN) dis[i] = 1.0 / sqrt((double)(deg[i] + 1));  // +1 = self loop
}

// ---------------- exclusive scan of deg -> row_ptr (3 kernels) ----------------

__global__ __launch_bounds__(256) void k_scan1(const int* __restrict__ deg,
                                               int* __restrict__ rp,
                                               int* __restrict__ bsum) {
    __shared__ int s[256];
    int t = threadIdx.x;
    int base = blockIdx.x * 1024 + t * 4;
    int v[4], sum = 0;
#pragma unroll
    for (int i = 0; i < 4; ++i) { int n = base + i; v[i] = (n < NN) ? deg[n] : 0; sum += v[i]; }
    s[t] = sum;
    __syncthreads();
    for (int off = 1; off < 256; off <<= 1) {
        int x = (t >= off) ? s[t - off] : 0;
        __syncthreads();
        s[t] += x;
        __syncthreads();
    }
    int excl = s[t] - sum;
    if (t == 255) bsum[blockIdx.x] = s[255];
    int run = excl;
#pragma unroll
    for (int i = 0; i < 4; ++i) { int n = base + i; if (n < NN) rp[n] = run; run += v[i]; }
}

__global__ void k_scan2(int* __restrict__ bsum, int* __restrict__ rp) {
    if (threadIdx.x == 0 && blockIdx.x == 0) {
        int acc = 0;
        for (int i = 0; i < NB; ++i) { int t = bsum[i]; bsum[i] = acc; acc += t; }
        rp[NN] = NE;
    }
}

__global__ __launch_bounds__(256) void k_scan3(int* __restrict__ rp,
                                               const int* __restrict__ bsum,
                                               int* __restrict__ cursor) {
    int n = blockIdx.x * 256 + threadIdx.x;
    if (n < NN) {
        int v = rp[n] + bsum[n >> 10];
        rp[n] = v;
        cursor[n] = v;
    }
}

// ---------------- CSR fill (order within a node nondeterministic; f64 sums absorb it) ----

__global__ __launch_bounds__(256) void k_fill(const int* __restrict__ ei,
                                              int* __restrict__ cursor,
                                              int* __restrict__ csr) {
    int e = blockIdx.x * 256 + threadIdx.x;
    if (e < NE) {
        int s = ei[e];
        int d = ei[NE + e];
        int pos = atomicAdd(&cursor[d], 1);
        csr[pos] = s;
    }
}

// ---------------- h2s = (in @ W) * dis[row]  (f64 acc, f32 out, no bias) ----------------

__global__ __launch_bounds__(256) void k_gemm(const float* __restrict__ in,
                                              const float* __restrict__ W,
                                              const double* __restrict__ dis,
                                              float* __restrict__ h2s) {
    __shared__ float sW[DD * DD];
    __shared__ float sIn[4][DD];
    int t = threadIdx.x;
    for (int i = t; i < DD * DD; i += 256) sW[i] = W[i];
    int r = t >> 6, c = t & 63;
    int row = blockIdx.x * 4 + r;       // NN % 4 == 0
    sIn[r][c] = in[row * DD + c];
    __syncthreads();
    double acc = 0.0;
#pragma unroll
    for (int k = 0; k < DD; ++k) acc += (double)sIn[r][k] * (double)sW[k * DD + c];
    h2s[row * DD + c] = (float)(acc * dis[row]);
}

// ---------------- gather-aggregate + bias + ELU: one wave per node ----------------

__global__ __launch_bounds__(256) void k_aggr(const int* __restrict__ rp,
                                              const int* __restrict__ csr,
                                              const float* __restrict__ h2s,
                                              const double* __restrict__ dis,
                                              const float* __restrict__ b,
                                              float* __restrict__ out,
                                              int apply_elu) {
    int gid = blockIdx.x * 256 + threadIdx.x;   // < NN*64
    int node = gid >> 6;
    int f = gid & 63;
    int beg = rp[node], end = rp[node + 1];
    double acc = (double)h2s[node * DD + f];    // self loop: dis[d]*h2s[d] = dis^2*h2
    for (int j = beg; j < end; ++j) {
        int s = csr[j];                          // uniform across the wave
        acc += (double)h2s[s * DD + f];
    }
    double v = dis[node] * acc + (double)b[f];
    if (apply_elu) v = (v > 0.0) ? v : expm1(v);
    out[gid] = (float)v;
}

// ---------------- launch ----------------

extern "C" void kernel_launch(void* const* d_in, const int* in_sizes, int n_in,
                              void* d_out, int out_size, void* d_ws, size_t ws_size,
                              hipStream_t stream) {
    const float* x  = (const float*)d_in[0];
    const int*   ei = (const int*)d_in[1];
    const float* W1 = (const float*)d_in[3];
    const float* b1 = (const float*)d_in[4];
    const float* W2 = (const float*)d_in[5];
    const float* b2 = (const float*)d_in[6];
    const float* W3 = (const float*)d_in[7];
    const float* b3 = (const float*)d_in[8];
    const float* W4 = (const float*)d_in[9];
    const float* b4 = (const float*)d_in[10];
    float* out = (float*)d_out;

    char* ws = (char*)d_ws;
    size_t off = 0;
    double* dis    = (double*)(ws + off); off += (size_t)NN * sizeof(double);
    float*  h2s    = (float*) (ws + off); off += (size_t)NN * DD * sizeof(float);
    float*  A      = (float*) (ws + off); off += (size_t)NN * DD * sizeof(float);
    int*    deg    = (int*)   (ws + off); off += (size_t)NN * sizeof(int);
    int*    cursor = (int*)   (ws + off); off += (size_t)NN * sizeof(int);
    int*    rp     = (int*)   (ws + off); off += (size_t)(NN + 1) * sizeof(int);
    int*    bsum   = (int*)   (ws + off); off += 128 * sizeof(int);
    int*    csr    = (int*)   (ws + off); off += (size_t)NE * sizeof(int);
    // total ~59.6 MB

    hipMemsetAsync(deg, 0, (size_t)NN * sizeof(int), stream);
    k_count<<<(NE + 255) / 256, 256, 0, stream>>>(ei, deg);
    k_dis<<<(NN + 255) / 256, 256, 0, stream>>>(deg, dis);
    k_scan1<<<NB, 256, 0, stream>>>(deg, rp, bsum);
    k_scan2<<<1, 64, 0, stream>>>(bsum, rp);
    k_scan3<<<(NN + 255) / 256, 256, 0, stream>>>(rp, bsum, cursor);
    k_fill<<<(NE + 255) / 256, 256, 0, stream>>>(ei, cursor, csr);

    struct Layer { const float* in; const float* b; const float* W; float* o; int elu; };
    Layer L[4] = {
        { x,   b1, W1, A,   1 },
        { A,   b2, W2, out, 1 },
        { out, b3, W3, A,   1 },
        { A,   b4, W4, out, 0 },
    };

    for (int l = 0; l < 4; ++l) {
        k_gemm<<<NN / 4, 256, 0, stream>>>(L[l].in, L[l].W, dis, h2s);
        k_aggr<<<NN * DD / 256, 256, 0, stream>>>(rp, csr, h2s, dis, L[l].b, L[l].o, L[l].elu);
    }
}

// Round 3
// 799.956 us; speedup vs baseline: 3.3808x; 1.3000x over previous
//
#include <hip/hip_runtime.h>

#define NN 100000
#define NE 1600000
#define DD 64
#define NB 98           // ceil(NN/1024) scan blocks

// ---------------- degree / normalization ----------------

__global__ __launch_bounds__(256) void k_count(const int* __restrict__ ei,
                                               int* __restrict__ deg) {
    int e = blockIdx.x * 256 + threadIdx.x;
    if (e < NE) atomicAdd(&deg[ei[NE + e]], 1);
}

__global__ __launch_bounds__(256) void k_dis(const int* __restrict__ deg,
                                             double* __restrict__ dis) {
    int i = blockIdx.x * 256 + threadIdx.x;
    if (i < NN) dis[i] = 1.0 / sqrt((double)(deg[i] + 1));  // +1 = self loop
}

// ---------------- exclusive scan of deg -> row_ptr ----------------

__global__ __launch_bounds__(256) void k_scan1(const int* __restrict__ deg,
                                               int* __restrict__ rp,
                                               int* __restrict__ bsum) {
    __shared__ int s[256];
    int t = threadIdx.x;
    int base = blockIdx.x * 1024 + t * 4;
    int v[4], sum = 0;
#pragma unroll
    for (int i = 0; i < 4; ++i) { int n = base + i; v[i] = (n < NN) ? deg[n] : 0; sum += v[i]; }
    s[t] = sum;
    __syncthreads();
    for (int off = 1; off < 256; off <<= 1) {
        int x = (t >= off) ? s[t - off] : 0;
        __syncthreads();
        s[t] += x;
        __syncthreads();
    }
    int excl = s[t] - sum;
    if (t == 255) bsum[blockIdx.x] = s[255];
    int run = excl;
#pragma unroll
    for (int i = 0; i < 4; ++i) { int n = base + i; if (n < NN) rp[n] = run; run += v[i]; }
}

__global__ void k_scan2(int* __restrict__ bsum, int* __restrict__ rp) {
    if (threadIdx.x == 0 && blockIdx.x == 0) {
        int acc = 0;
        for (int i = 0; i < NB; ++i) { int t = bsum[i]; bsum[i] = acc; acc += t; }
        rp[NN] = NE;
    }
}

__global__ __launch_bounds__(256) void k_scan3(int* __restrict__ rp,
                                               const int* __restrict__ bsum,
                                               int* __restrict__ cursor) {
    int n = blockIdx.x * 256 + threadIdx.x;
    if (n < NN) {
        int v = rp[n] + bsum[n >> 10];
        rp[n] = v;
        cursor[n] = v;
    }
}

// ---------------- CSR fill ----------------

__global__ __launch_bounds__(256) void k_fill(const int* __restrict__ ei,
                                              int* __restrict__ cursor,
                                              int* __restrict__ csr) {
    int e = blockIdx.x * 256 + threadIdx.x;
    if (e < NE) {
        int s = ei[e];
        int d = ei[NE + e];
        int pos = atomicAdd(&cursor[d], 1);
        csr[pos] = s;
    }
}

// ---------------- h2s = (in @ W) * dis[row]  (f32 FMA, 8-way split acc) ----------------

__global__ __launch_bounds__(256) void k_gemm(const float* __restrict__ in,
                                              const float* __restrict__ W,
                                              const double* __restrict__ dis,
                                              float* __restrict__ h2s) {
    __shared__ float sW[DD * DD];
    __shared__ float sIn[4][DD];
    int t = threadIdx.x;
    for (int i = t; i < DD * DD; i += 256) sW[i] = W[i];
    int r = t >> 6, c = t & 63;
    int row = blockIdx.x * 4 + r;       // NN % 4 == 0
    sIn[r][c] = in[row * DD + c];
    __syncthreads();
    float a[8] = {0.f, 0.f, 0.f, 0.f, 0.f, 0.f, 0.f, 0.f};
#pragma unroll
    for (int k0 = 0; k0 < DD; k0 += 8) {
#pragma unroll
        for (int kk = 0; kk < 8; ++kk)
            a[kk] = fmaf(sIn[r][k0 + kk], sW[(k0 + kk) * DD + c], a[kk]);
    }
    float s = ((a[0] + a[1]) + (a[2] + a[3])) + ((a[4] + a[5]) + (a[6] + a[7]));
    h2s[row * DD + c] = (float)((double)s * dis[row]);
}

// ---------------- gather-aggregate, 4 rows in flight per wave ----------------
// lane = 16*q + c : group q in 0..3 handles virtual-neighbor slot j0+q,
// lane covers features c*4..c*4+3 via one float4 (16 lanes x 16B = 256B row).

__global__ __launch_bounds__(256) void k_aggr(const int* __restrict__ rp,
                                              const int* __restrict__ csr,
                                              const float* __restrict__ h2s,
                                              const double* __restrict__ dis,
                                              const float* __restrict__ b,
                                              float* __restrict__ out,
                                              int apply_elu) {
    int gid = blockIdx.x * 256 + threadIdx.x;
    int node = gid >> 6;
    int lane = gid & 63;
    int q = lane >> 4;
    int c = lane & 15;
    int beg = rp[node];
    int len = rp[node + 1] - beg + 1;          // +1 = self loop (virtual entry 0)
    double dn = dis[node];

    double acc0 = 0.0, acc1 = 0.0, acc2 = 0.0, acc3 = 0.0;
    for (int j0 = 0; j0 < len; j0 += 4) {
        int j = j0 + q;
        bool valid = j < len;
        int s = node;
        if (valid && j > 0) s = csr[beg + j - 1];
        float4 v = *(const float4*)&h2s[(size_t)s * DD + c * 4];
        if (valid) {
            acc0 += (double)v.x;
            acc1 += (double)v.y;
            acc2 += (double)v.z;
            acc3 += (double)v.w;
        }
    }
    // combine the 4 q-groups (lane bits 4,5)
    acc0 += __shfl_xor(acc0, 16); acc0 += __shfl_xor(acc0, 32);
    acc1 += __shfl_xor(acc1, 16); acc1 += __shfl_xor(acc1, 32);
    acc2 += __shfl_xor(acc2, 16); acc2 += __shfl_xor(acc2, 32);
    acc3 += __shfl_xor(acc3, 16); acc3 += __shfl_xor(acc3, 32);

    if (q == 0) {
        float4 bb = *(const float4*)&b[c * 4];
        double v0 = dn * acc0 + (double)bb.x;
        double v1 = dn * acc1 + (double)bb.y;
        double v2 = dn * acc2 + (double)bb.z;
        double v3 = dn * acc3 + (double)bb.w;
        if (apply_elu) {
            v0 = (v0 > 0.0) ? v0 : expm1(v0);
            v1 = (v1 > 0.0) ? v1 : expm1(v1);
            v2 = (v2 > 0.0) ? v2 : expm1(v2);
            v3 = (v3 > 0.0) ? v3 : expm1(v3);
        }
        float4 r = make_float4((float)v0, (float)v1, (float)v2, (float)v3);
        *(float4*)&out[(size_t)node * DD + c * 4] = r;
    }
}

// ---------------- launch ----------------

extern "C" void kernel_launch(void* const* d_in, const int* in_sizes, int n_in,
                              void* d_out, int out_size, void* d_ws, size_t ws_size,
                              hipStream_t stream) {
    const float* x  = (const float*)d_in[0];
    const int*   ei = (const int*)d_in[1];
    const float* W1 = (const float*)d_in[3];
    const float* b1 = (const float*)d_in[4];
    const float* W2 = (const float*)d_in[5];
    const float* b2 = (const float*)d_in[6];
    const float* W3 = (const float*)d_in[7];
    const float* b3 = (const float*)d_in[8];
    const float* W4 = (const float*)d_in[9];
    const float* b4 = (const float*)d_in[10];
    float* out = (float*)d_out;

    char* ws = (char*)d_ws;
    size_t off = 0;
    double* dis    = (double*)(ws + off); off += (size_t)NN * sizeof(double);
    float*  h2s    = (float*) (ws + off); off += (size_t)NN * DD * sizeof(float);
    float*  A      = (float*) (ws + off); off += (size_t)NN * DD * sizeof(float);
    int*    deg    = (int*)   (ws + off); off += (size_t)NN * sizeof(int);
    int*    cursor = (int*)   (ws + off); off += (size_t)NN * sizeof(int);
    int*    rp     = (int*)   (ws + off); off += (size_t)(NN + 1) * sizeof(int);
    int*    bsum   = (int*)   (ws + off); off += 128 * sizeof(int);
    int*    csr    = (int*)   (ws + off); off += (size_t)NE * sizeof(int);

    hipMemsetAsync(deg, 0, (size_t)NN * sizeof(int), stream);
    k_count<<<(NE + 255) / 256, 256, 0, stream>>>(ei, deg);
    k_dis<<<(NN + 255) / 256, 256, 0, stream>>>(deg, dis);
    k_scan1<<<NB, 256, 0, stream>>>(deg, rp, bsum);
    k_scan2<<<1, 64, 0, stream>>>(bsum, rp);
    k_scan3<<<(NN + 255) / 256, 256, 0, stream>>>(rp, bsum, cursor);
    k_fill<<<(NE + 255) / 256, 256, 0, stream>>>(ei, cursor, csr);

    struct Layer { const float* in; const float* b; const float* W; float* o; int elu; };
    Layer L[4] = {
        { x,   b1, W1, A,   1 },
        { A,   b2, W2, out, 1 },
        { out, b3, W3, A,   1 },
        { A,   b4, W4, out, 0 },
    };

    for (int l = 0; l < 4; ++l) {
        k_gemm<<<NN / 4, 256, 0, stream>>>(L[l].in, L[l].W, dis, h2s);
        k_aggr<<<NN / 4, 256, 0, stream>>>(rp, csr, h2s, dis, L[l].b, L[l].o, L[l].elu);
    }
}

// Round 4
// 542.579 us; speedup vs baseline: 4.9844x; 1.4744x over previous
//
#include <hip/hip_runtime.h>

#define NN 100000
#define NE 1600000
#define DD 64
#define NB 98           // ceil(NN/1024) scan blocks
#define NPASS 4
#define PRANGE (NN / NPASS)   // 25000

// ---------------- degree / normalization ----------------

__global__ __launch_bounds__(256) void k_count(const int* __restrict__ ei,
                                               int* __restrict__ deg) {
    int e = blockIdx.x * 256 + threadIdx.x;
    if (e < NE) atomicAdd(&deg[ei[NE + e]], 1);
}

__global__ __launch_bounds__(256) void k_dis(const int* __restrict__ deg,
                                             double* __restrict__ dis) {
    int i = blockIdx.x * 256 + threadIdx.x;
    if (i < NN) dis[i] = 1.0 / sqrt((double)(deg[i] + 1));  // +1 = self loop
}

// ---------------- exclusive scan of deg -> row_ptr ----------------

__global__ __launch_bounds__(256) void k_scan1(const int* __restrict__ deg,
                                               int* __restrict__ rp,
                                               int* __restrict__ bsum) {
    __shared__ int s[256];
    int t = threadIdx.x;
    int base = blockIdx.x * 1024 + t * 4;
    int v[4], sum = 0;
#pragma unroll
    for (int i = 0; i < 4; ++i) { int n = base + i; v[i] = (n < NN) ? deg[n] : 0; sum += v[i]; }
    s[t] = sum;
    __syncthreads();
    for (int off = 1; off < 256; off <<= 1) {
        int x = (t >= off) ? s[t - off] : 0;
        __syncthreads();
        s[t] += x;
        __syncthreads();
    }
    int excl = s[t] - sum;
    if (t == 255) bsum[blockIdx.x] = s[255];
    int run = excl;
#pragma unroll
    for (int i = 0; i < 4; ++i) { int n = base + i; if (n < NN) rp[n] = run; run += v[i]; }
}

__global__ void k_scan2(int* __restrict__ bsum, int* __restrict__ rp) {
    if (threadIdx.x == 0 && blockIdx.x == 0) {
        int acc = 0;
        for (int i = 0; i < NB; ++i) { int t = bsum[i]; bsum[i] = acc; acc += t; }
        rp[NN] = NE;
    }
}

__global__ __launch_bounds__(256) void k_scan3(int* __restrict__ rp,
                                               const int* __restrict__ bsum,
                                               int* __restrict__ cursor) {
    int n = blockIdx.x * 256 + threadIdx.x;
    if (n < NN) {
        int v = rp[n] + bsum[n >> 10];
        rp[n] = v;
        cursor[n] = v;
    }
}

// ---------------- CSR fill, one dst-range per pass (L2-resident writes) ----------------

__global__ __launch_bounds__(256) void k_fillp(const int* __restrict__ ei,
                                               int* __restrict__ cursor,
                                               int* __restrict__ csr,
                                               int lo, int hi) {
    int e = blockIdx.x * 256 + threadIdx.x;
    if (e < NE) {
        int d = ei[NE + e];
        if (d >= lo && d < hi) {
            int s = ei[e];
            int pos = atomicAdd(&cursor[d], 1);
            csr[pos] = s;
        }
    }
}

// ---------------- h2s = (in @ W) * dis[row] ----------------
// 256 thr = 16 rows; thread t: row r = t>>4, cols cg*4..cg*4+3 (cg = t&15).
// 8-way split f32 accumulators; f64 only for the final dis scale.

__global__ __launch_bounds__(256) void k_gemm(const float* __restrict__ in,
                                              const float* __restrict__ W,
                                              const double* __restrict__ dis,
                                              float* __restrict__ h2s) {
    __shared__ float sW[DD * DD];
    __shared__ float sIn[16][DD];
    int t = threadIdx.x;
    int brow = blockIdx.x * 16;          // NN % 16 == 0
#pragma unroll
    for (int i = 0; i < 16; ++i) sW[t + 256 * i] = W[t + 256 * i];
#pragma unroll
    for (int i = 0; i < 4; ++i) {
        int idx = t + 256 * i;           // 0..1023
        sIn[idx >> 6][idx & 63] = in[(size_t)brow * DD + idx];
    }
    __syncthreads();
    int r = t >> 4, cg = t & 15;
    float acc[4][8];
#pragma unroll
    for (int j = 0; j < 4; ++j)
#pragma unroll
        for (int kk = 0; kk < 8; ++kk) acc[j][kk] = 0.f;

#pragma unroll
    for (int k0 = 0; k0 < DD; k0 += 8) {
#pragma unroll
        for (int kk = 0; kk < 8; ++kk) {
            int k = k0 + kk;
            float a = sIn[r][k];
            float4 w = *(const float4*)&sW[k * DD + cg * 4];
            acc[0][kk] = fmaf(a, w.x, acc[0][kk]);
            acc[1][kk] = fmaf(a, w.y, acc[1][kk]);
            acc[2][kk] = fmaf(a, w.z, acc[2][kk]);
            acc[3][kk] = fmaf(a, w.w, acc[3][kk]);
        }
    }
    double dr = dis[brow + r];
    float4 o;
    float* op = &o.x;
#pragma unroll
    for (int j = 0; j < 4; ++j) {
        float s = ((acc[j][0] + acc[j][1]) + (acc[j][2] + acc[j][3]))
                + ((acc[j][4] + acc[j][5]) + (acc[j][6] + acc[j][7]));
        op[j] = (float)((double)s * dr);
    }
    *(float4*)&h2s[(size_t)(brow + r) * DD + cg * 4] = o;
}

// ---------------- gather-aggregate, 8 rows in flight per wave ----------------
// lane = 8*q + c : group q (0..7) handles virtual-neighbor slot j0+q,
// lane covers features c*8..c*8+7 via two float4 (8 lanes x 32B = 256B row).

__global__ __launch_bounds__(256) void k_aggr(const int* __restrict__ rp,
                                              const int* __restrict__ csr,
                                              const float* __restrict__ h2s,
                                              const double* __restrict__ dis,
                                              const float* __restrict__ b,
                                              float* __restrict__ out,
                                              int apply_elu) {
    int gid = blockIdx.x * 256 + threadIdx.x;
    int node = gid >> 6;
    int lane = gid & 63;
    int q = lane >> 3;
    int c = lane & 7;
    int beg = rp[node];
    int len = rp[node + 1] - beg + 1;          // +1 = self loop (virtual entry 0)
    double dn = dis[node];

    double a[8];
#pragma unroll
    for (int i = 0; i < 8; ++i) a[i] = 0.0;

    for (int j0 = 0; j0 < len; j0 += 8) {
        int j = j0 + q;
        bool valid = j < len;
        int s = node;
        if (valid && j > 0) s = csr[beg + j - 1];
        const float4* p = (const float4*)&h2s[(size_t)s * DD + c * 8];
        float4 v0 = p[0];
        float4 v1 = p[1];
        if (valid) {
            a[0] += (double)v0.x; a[1] += (double)v0.y;
            a[2] += (double)v0.z; a[3] += (double)v0.w;
            a[4] += (double)v1.x; a[5] += (double)v1.y;
            a[6] += (double)v1.z; a[7] += (double)v1.w;
        }
    }
    // combine the 8 q-groups (lane bits 3,4,5)
#pragma unroll
    for (int i = 0; i < 8; ++i) {
        a[i] += __shfl_xor(a[i], 8);
        a[i] += __shfl_xor(a[i], 16);
        a[i] += __shfl_xor(a[i], 32);
    }

    if (q == 0) {
        float4 b0 = *(const float4*)&b[c * 8];
        float4 b1 = *(const float4*)&b[c * 8 + 4];
        const float* bp0 = &b0.x;
        const float* bp1 = &b1.x;
        float4 o0, o1;
        float* o0p = &o0.x;
        float* o1p = &o1.x;
#pragma unroll
        for (int i = 0; i < 4; ++i) {
            float vf = (float)(dn * a[i] + (double)bp0[i]);
            o0p[i] = (apply_elu && vf <= 0.f) ? expm1f(vf) : vf;
        }
#pragma unroll
        for (int i = 0; i < 4; ++i) {
            float vf = (float)(dn * a[i + 4] + (double)bp1[i]);
            o1p[i] = (apply_elu && vf <= 0.f) ? expm1f(vf) : vf;
        }
        *(float4*)&out[(size_t)node * DD + c * 8] = o0;
        *(float4*)&out[(size_t)node * DD + c * 8 + 4] = o1;
    }
}

// ---------------- launch ----------------

extern "C" void kernel_launch(void* const* d_in, const int* in_sizes, int n_in,
                              void* d_out, int out_size, void* d_ws, size_t ws_size,
                              hipStream_t stream) {
    const float* x  = (const float*)d_in[0];
    const int*   ei = (const int*)d_in[1];
    const float* W1 = (const float*)d_in[3];
    const float* b1 = (const float*)d_in[4];
    const float* W2 = (const float*)d_in[5];
    const float* b2 = (const float*)d_in[6];
    const float* W3 = (const float*)d_in[7];
    const float* b3 = (const float*)d_in[8];
    const float* W4 = (const float*)d_in[9];
    const float* b4 = (const float*)d_in[10];
    float* out = (float*)d_out;

    char* ws = (char*)d_ws;
    size_t off = 0;
    double* dis    = (double*)(ws + off); off += (size_t)NN * sizeof(double);
    float*  h2s    = (float*) (ws + off); off += (size_t)NN * DD * sizeof(float);
    float*  A      = (float*) (ws + off); off += (size_t)NN * DD * sizeof(float);
    int*    deg    = (int*)   (ws + off); off += (size_t)NN * sizeof(int);
    int*    cursor = (int*)   (ws + off); off += (size_t)NN * sizeof(int);
    int*    rp     = (int*)   (ws + off); off += (size_t)(NN + 1) * sizeof(int);
    int*    bsum   = (int*)   (ws + off); off += 128 * sizeof(int);
    int*    csr    = (int*)   (ws + off); off += (size_t)NE * sizeof(int);

    hipMemsetAsync(deg, 0, (size_t)NN * sizeof(int), stream);
    k_count<<<(NE + 255) / 256, 256, 0, stream>>>(ei, deg);
    k_dis<<<(NN + 255) / 256, 256, 0, stream>>>(deg, dis);
    k_scan1<<<NB, 256, 0, stream>>>(deg, rp, bsum);
    k_scan2<<<1, 64, 0, stream>>>(bsum, rp);
    k_scan3<<<(NN + 255) / 256, 256, 0, stream>>>(rp, bsum, cursor);
    for (int p = 0; p < NPASS; ++p)
        k_fillp<<<(NE + 255) / 256, 256, 0, stream>>>(ei, cursor, csr,
                                                      p * PRANGE, (p + 1) * PRANGE);

    struct Layer { const float* in; const float* b; const float* W; float* o; int elu; };
    Layer L[4] = {
        { x,   b1, W1, A,   1 },
        { A,   b2, W2, out, 1 },
        { out, b3, W3, A,   1 },
        { A,   b4, W4, out, 0 },
    };

    for (int l = 0; l < 4; ++l) {
        k_gemm<<<NN / 16, 256, 0, stream>>>(L[l].in, L[l].W, dis, h2s);
        k_aggr<<<NN / 4, 256, 0, stream>>>(rp, csr, h2s, dis, L[l].b, L[l].o, L[l].elu);
    }
}

// Round 5
// 506.416 us; speedup vs baseline: 5.3404x; 1.0714x over previous
//
#include <hip/hip_runtime.h>

#define NN 100000
#define NE 1600000
#define DD 64
#define NB 98           // ceil(NN/1024) scan blocks
#define NPASS 4
#define PRANGE (NN / NPASS)   // 25000
#define CSR2_CAP (NE + 8 * NN)  // sum of padded rows <= E + 8N

// ---------------- degree ----------------

__global__ __launch_bounds__(256) void k_count(const int* __restrict__ ei,
                                               int* __restrict__ deg) {
    int e = blockIdx.x * 256 + threadIdx.x;
    if (e < NE) atomicAdd(&deg[ei[NE + e]], 1);
}

__global__ __launch_bounds__(256) void k_dis(const int* __restrict__ deg,
                                             double* __restrict__ dis) {
    int i = blockIdx.x * 256 + threadIdx.x;
    if (i < NN) dis[i] = 1.0 / sqrt((double)(deg[i] + 1));  // +1 = self loop
}

// ---------------- exclusive scan of PADDED degree -> rp2 ----------------
// pdeg[n] = ceil((deg[n]+1)/8)*8  (self loop + pad to multiple of 8)

__global__ __launch_bounds__(256) void k_scan1(const int* __restrict__ deg,
                                               int* __restrict__ rp,
                                               int* __restrict__ bsum) {
    __shared__ int s[256];
    int t = threadIdx.x;
    int base = blockIdx.x * 1024 + t * 4;
    int v[4], sum = 0;
#pragma unroll
    for (int i = 0; i < 4; ++i) {
        int n = base + i;
        v[i] = (n < NN) ? ((deg[n] + 8) & ~7) : 0;
        sum += v[i];
    }
    s[t] = sum;
    __syncthreads();
    for (int off = 1; off < 256; off <<= 1) {
        int x = (t >= off) ? s[t - off] : 0;
        __syncthreads();
        s[t] += x;
        __syncthreads();
    }
    int excl = s[t] - sum;
    if (t == 255) bsum[blockIdx.x] = s[255];
    int run = excl;
#pragma unroll
    for (int i = 0; i < 4; ++i) { int n = base + i; if (n < NN) rp[n] = run; run += v[i]; }
}

__global__ void k_scan2(int* __restrict__ bsum, int* __restrict__ rp) {
    if (threadIdx.x == 0 && blockIdx.x == 0) {
        int acc = 0;
        for (int i = 0; i < NB; ++i) { int t = bsum[i]; bsum[i] = acc; acc += t; }
        rp[NN] = acc;   // total padded entries
    }
}

// finalize rp2, init cursor past the self entry, write self entry
__global__ __launch_bounds__(256) void k_scan3(int* __restrict__ rp,
                                               const int* __restrict__ bsum,
                                               int* __restrict__ cursor,
                                               int* __restrict__ csr2) {
    int n = blockIdx.x * 256 + threadIdx.x;
    if (n < NN) {
        int v = rp[n] + bsum[n >> 10];
        rp[n] = v;
        cursor[n] = v + 1;   // slot 0 = self
        csr2[v] = n;
    }
}

// ---------------- CSR fill, one dst-range per pass (L2-resident writes) ----------------

__global__ __launch_bounds__(256) void k_fillp(const int* __restrict__ ei,
                                               int* __restrict__ cursor,
                                               int* __restrict__ csr2,
                                               int lo, int hi) {
    int e = blockIdx.x * 256 + threadIdx.x;
    if (e < NE) {
        int d = ei[NE + e];
        if (d >= lo && d < hi) {
            int s = ei[e];
            int pos = atomicAdd(&cursor[d], 1);
            csr2[pos] = s;
        }
    }
}

// pad tail of each row with dummy index NN (points at a zero row of h2s)
__global__ __launch_bounds__(256) void k_pad(const int* __restrict__ cursor,
                                             const int* __restrict__ rp2,
                                             int* __restrict__ csr2) {
    int n = blockIdx.x * 256 + threadIdx.x;
    if (n < NN) {
        int e = rp2[n + 1];
        for (int j = cursor[n]; j < e; ++j) csr2[j] = NN;
    }
}

// ---------------- h2s = (in @ W) * dis[row] ----------------
// 128 rows/block; thread t: rows (t>>3)*4..+3, cols (t&7)*8..+7.
// sIn padded to 65 floats/row (bank-conflict-free ds_read2_b32 on rows).
// 2-way k-split f32 accumulators; f64 only for the final dis scale.

__global__ __launch_bounds__(256) void k_gemm(const float* __restrict__ in,
                                              const float* __restrict__ W,
                                              const double* __restrict__ dis,
                                              float* __restrict__ h2s) {
    __shared__ float sW[DD * DD];        // 16 KB
    __shared__ float sIn[128 * 65];      // 33.3 KB
    int t = threadIdx.x;
    int brow = blockIdx.x * 128;
#pragma unroll
    for (int i = 0; i < 16; ++i) sW[t + 256 * i] = W[t + 256 * i];
#pragma unroll
    for (int i = 0; i < 32; ++i) {
        int idx = t + 256 * i;
        int rr = idx >> 6, kk = idx & 63;
        int gr = brow + rr; if (gr >= NN) gr = NN - 1;   // clamp (last block)
        sIn[rr * 65 + kk] = in[(size_t)gr * DD + kk];
    }
    __syncthreads();
    int cg = t & 7;
    int rg = t >> 3;
    const float* sInB = &sIn[rg * 4 * 65];

    float aE[4][8], aO[4][8];
#pragma unroll
    for (int i = 0; i < 4; ++i)
#pragma unroll
        for (int j = 0; j < 8; ++j) { aE[i][j] = 0.f; aO[i][j] = 0.f; }

#pragma unroll 4
    for (int k = 0; k < DD; k += 2) {
        float4 w0 = *(const float4*)&sW[k * DD + cg * 8];
        float4 w1 = *(const float4*)&sW[k * DD + cg * 8 + 4];
        float4 w2 = *(const float4*)&sW[(k + 1) * DD + cg * 8];
        float4 w3 = *(const float4*)&sW[(k + 1) * DD + cg * 8 + 4];
        float wv0[8] = {w0.x, w0.y, w0.z, w0.w, w1.x, w1.y, w1.z, w1.w};
        float wv1[8] = {w2.x, w2.y, w2.z, w2.w, w3.x, w3.y, w3.z, w3.w};
#pragma unroll
        for (int i = 0; i < 4; ++i) {
            float a0 = sInB[i * 65 + k];
            float a1 = sInB[i * 65 + k + 1];
#pragma unroll
            for (int j = 0; j < 8; ++j) {
                aE[i][j] = fmaf(a0, wv0[j], aE[i][j]);
                aO[i][j] = fmaf(a1, wv1[j], aO[i][j]);
            }
        }
    }

#pragma unroll
    for (int i = 0; i < 4; ++i) {
        int row = brow + rg * 4 + i;
        if (row < NN) {
            double dr = dis[row];
            float o[8];
#pragma unroll
            for (int j = 0; j < 8; ++j)
                o[j] = (float)((double)(aE[i][j] + aO[i][j]) * dr);
            float4 o0 = make_float4(o[0], o[1], o[2], o[3]);
            float4 o1 = make_float4(o[4], o[5], o[6], o[7]);
            *(float4*)&h2s[(size_t)row * DD + cg * 8] = o0;
            *(float4*)&h2s[(size_t)row * DD + cg * 8 + 4] = o1;
        }
    }
}

// ---------------- gather-aggregate: lane = feature, padded CSR, no shuffles ----------------

__global__ __launch_bounds__(256) void k_aggr(const int* __restrict__ rp2,
                                              const int* __restrict__ csr2,
                                              const float* __restrict__ h2s,
                                              const double* __restrict__ dis,
                                              const float* __restrict__ b,
                                              float* __restrict__ out,
                                              int apply_elu) {
    int gid = blockIdx.x * 256 + threadIdx.x;
    int node = gid >> 6;
    int lane = gid & 63;
    int beg = __builtin_amdgcn_readfirstlane(rp2[node]);
    int end = __builtin_amdgcn_readfirstlane(rp2[node + 1]);
    double a0 = 0.0, a1 = 0.0;
    for (int j = beg; j < end; j += 8) {
        int4 i0 = *(const int4*)&csr2[j];       // 32B-aligned, uniform -> s_load
        int4 i1 = *(const int4*)&csr2[j + 4];
        float v0 = h2s[(size_t)(unsigned)i0.x * DD + lane];
        float v1 = h2s[(size_t)(unsigned)i0.y * DD + lane];
        float v2 = h2s[(size_t)(unsigned)i0.z * DD + lane];
        float v3 = h2s[(size_t)(unsigned)i0.w * DD + lane];
        float v4 = h2s[(size_t)(unsigned)i1.x * DD + lane];
        float v5 = h2s[(size_t)(unsigned)i1.y * DD + lane];
        float v6 = h2s[(size_t)(unsigned)i1.z * DD + lane];
        float v7 = h2s[(size_t)(unsigned)i1.w * DD + lane];
        a0 += (double)v0; a1 += (double)v1;
        a0 += (double)v2; a1 += (double)v3;
        a0 += (double)v4; a1 += (double)v5;
        a0 += (double)v6; a1 += (double)v7;
    }
    float vf = (float)(dis[node] * (a0 + a1) + (double)b[lane]);
    if (apply_elu && vf <= 0.f) vf = expm1f(vf);
    out[gid] = vf;
}

// ---------------- launch ----------------

extern "C" void kernel_launch(void* const* d_in, const int* in_sizes, int n_in,
                              void* d_out, int out_size, void* d_ws, size_t ws_size,
                              hipStream_t stream) {
    const float* x  = (const float*)d_in[0];
    const int*   ei = (const int*)d_in[1];
    const float* W1 = (const float*)d_in[3];
    const float* b1 = (const float*)d_in[4];
    const float* W2 = (const float*)d_in[5];
    const float* b2 = (const float*)d_in[6];
    const float* W3 = (const float*)d_in[7];
    const float* b3 = (const float*)d_in[8];
    const float* W4 = (const float*)d_in[9];
    const float* b4 = (const float*)d_in[10];
    float* out = (float*)d_out;

    char* ws = (char*)d_ws;
    size_t off = 0;
    double* dis    = (double*)(ws + off); off += (size_t)NN * sizeof(double);
    float*  h2s    = (float*) (ws + off); off += (size_t)(NN + 1) * DD * sizeof(float); // +1 dummy row
    float*  A      = (float*) (ws + off); off += (size_t)NN * DD * sizeof(float);
    int*    deg    = (int*)   (ws + off); off += (size_t)NN * sizeof(int);
    int*    cursor = (int*)   (ws + off); off += (size_t)NN * sizeof(int);
    int*    rp2    = (int*)   (ws + off); off += (size_t)(NN + 1) * sizeof(int);
    int*    bsum   = (int*)   (ws + off); off += 128 * sizeof(int);
    int*    csr2   = (int*)   (ws + off); off += (size_t)CSR2_CAP * sizeof(int);

    hipMemsetAsync(deg, 0, (size_t)NN * sizeof(int), stream);
    hipMemsetAsync(h2s + (size_t)NN * DD, 0, DD * sizeof(float), stream);  // dummy row = 0
    k_count<<<(NE + 255) / 256, 256, 0, stream>>>(ei, deg);
    k_dis<<<(NN + 255) / 256, 256, 0, stream>>>(deg, dis);
    k_scan1<<<NB, 256, 0, stream>>>(deg, rp2, bsum);
    k_scan2<<<1, 64, 0, stream>>>(bsum, rp2);
    k_scan3<<<(NN + 255) / 256, 256, 0, stream>>>(rp2, bsum, cursor, csr2);
    for (int p = 0; p < NPASS; ++p)
        k_fillp<<<(NE + 255) / 256, 256, 0, stream>>>(ei, cursor, csr2,
                                                      p * PRANGE, (p + 1) * PRANGE);
    k_pad<<<(NN + 255) / 256, 256, 0, stream>>>(cursor, rp2, csr2);

    struct Layer { const float* in; const float* b; const float* W; float* o; int elu; };
    Layer L[4] = {
        { x,   b1, W1, A,   1 },
        { A,   b2, W2, out, 1 },
        { out, b3, W3, A,   1 },
        { A,   b4, W4, out, 0 },
    };

    for (int l = 0; l < 4; ++l) {
        k_gemm<<<(NN + 127) / 128, 256, 0, stream>>>(L[l].in, L[l].W, dis, h2s);
        k_aggr<<<NN / 4, 256, 0, stream>>>(rp2, csr2, h2s, dis, L[l].b, L[l].o, L[l].elu);
    }
}

// Round 6
// 395.215 us; speedup vs baseline: 6.8430x; 1.2814x over previous
//
#include <hip/hip_runtime.h>

#define NN 100000
#define NE 1600000
#define DD 64
#define BSH 9
#define BSZ 512                      // nodes per bucket
#define NBKT 196                     // ceil(NN/BSZ)
#define CHUNK 8192                   // edges per scatter block
#define NCH ((NE + CHUNK - 1) / CHUNK)   // 196
#define CSR2_CAP (NE + 8 * (NBKT * BSZ))

// ---------------- P1: coarse bucket histogram ----------------

__global__ __launch_bounds__(256) void k_bcount(const int* __restrict__ ei,
                                                int* __restrict__ bcnt) {
    __shared__ int h[NBKT];
    int t = threadIdx.x;
    for (int i = t; i < NBKT; i += 256) h[i] = 0;
    __syncthreads();
    int base = blockIdx.x * CHUNK;
    for (int i = t; i < CHUNK; i += 256) {
        int e = base + i;
        if (e < NE) atomicAdd(&h[ei[NE + e] >> BSH], 1);
    }
    __syncthreads();
    for (int i = t; i < NBKT; i += 256)
        if (h[i]) atomicAdd(&bcnt[i], h[i]);
}

// ---------------- P1s: scan 196 bucket counts ----------------

__global__ void k_bscan(const int* __restrict__ bcnt,
                        int* __restrict__ bbase, int* __restrict__ bcur) {
    if (threadIdx.x == 0) {
        int acc = 0;
        for (int i = 0; i < NBKT; ++i) { bbase[i] = acc; bcur[i] = acc; acc += bcnt[i]; }
        bbase[NBKT] = acc;
    }
}

// ---------------- P2: scatter edges into bucket-grouped packed lists ----------------
// packed = s | (dlocal << 17);  s < 2^17, dlocal < 512.

__global__ __launch_bounds__(256) void k_bscat(const int* __restrict__ ei,
                                               int* __restrict__ bcur,
                                               int* __restrict__ bkt) {
    __shared__ int h[NBKT], rbase[NBKT], rcur[NBKT];
    int t = threadIdx.x;
    for (int i = t; i < NBKT; i += 256) h[i] = 0;
    __syncthreads();
    int cb = blockIdx.x * CHUNK;
    int s[32], d[32];
#pragma unroll
    for (int i = 0; i < 32; ++i) {
        int e = cb + t + 256 * i;
        if (e < NE) {
            s[i] = ei[e];
            d[i] = ei[NE + e];
            atomicAdd(&h[d[i] >> BSH], 1);
        } else {
            d[i] = -1;
        }
    }
    __syncthreads();
    for (int i = t; i < NBKT; i += 256) {
        int c = h[i];
        rbase[i] = c ? atomicAdd(&bcur[i], c) : 0;
        rcur[i] = 0;
    }
    __syncthreads();
#pragma unroll
    for (int i = 0; i < 32; ++i) {
        if (d[i] >= 0) {
            int b = d[i] >> BSH;
            int pos = rbase[b] + atomicAdd(&rcur[b], 1);
            bkt[pos] = s[i] | ((d[i] & (BSZ - 1)) << 17);
        }
    }
}

// ---------------- P3a: per-bucket node counts (LDS), dis, padded totals ----------------

__global__ __launch_bounds__(256) void k_ncnt(const int* __restrict__ bbase,
                                              const int* __restrict__ bkt,
                                              int* __restrict__ ncnt,
                                              int* __restrict__ bptot,
                                              double* __restrict__ dis) {
    __shared__ int cnt[BSZ];
    __shared__ int red[256];
    int b = blockIdx.x, t = threadIdx.x;
    cnt[t] = 0; cnt[t + 256] = 0;
    __syncthreads();
    int beg = bbase[b], end = bbase[b + 1];
    for (int j = beg + t; j < end; j += 256)
        atomicAdd(&cnt[bkt[j] >> 17], 1);
    __syncthreads();
    int nb = b * BSZ;
    int n0 = nb + t, n1 = nb + t + 256;
    int c0 = cnt[t], c1 = cnt[t + 256];
    int p0 = (n0 < NN) ? ((c0 + 8) & ~7) : 0;
    int p1 = (n1 < NN) ? ((c1 + 8) & ~7) : 0;
    if (n0 < NN) { ncnt[n0] = c0; dis[n0] = 1.0 / sqrt((double)(c0 + 1)); }
    if (n1 < NN) { ncnt[n1] = c1; dis[n1] = 1.0 / sqrt((double)(c1 + 1)); }
    red[t] = p0 + p1;
    __syncthreads();
    for (int o = 128; o > 0; o >>= 1) {
        if (t < o) red[t] += red[t + o];
        __syncthreads();
    }
    if (t == 0) bptot[b] = red[0];
}

// ---------------- P3b: scan padded bucket totals ----------------

__global__ void k_pscan(const int* __restrict__ bptot,
                        int* __restrict__ pbase, int* __restrict__ rp2) {
    if (threadIdx.x == 0) {
        int acc = 0;
        for (int i = 0; i < NBKT; ++i) { pbase[i] = acc; acc += bptot[i]; }
        rp2[NN] = acc;
    }
}

// ---------------- P3c: per-bucket rp2 + csr2 fill (LDS scan + LDS cursors) ----------------

__global__ __launch_bounds__(256) void k_bfill(const int* __restrict__ bbase,
                                               const int* __restrict__ bkt,
                                               const int* __restrict__ ncnt,
                                               const int* __restrict__ pbase,
                                               int* __restrict__ rp2,
                                               int* __restrict__ csr2) {
    __shared__ int cur[BSZ];
    __shared__ int s2[256];
    int b = blockIdx.x, t = threadIdx.x;
    int nb = b * BSZ;
    int gbase = pbase[b];
    int n0 = nb + 2 * t, n1 = nb + 2 * t + 1;
    int c0 = (n0 < NN) ? ncnt[n0] : -1;
    int c1 = (n1 < NN) ? ncnt[n1] : -1;
    int q0 = (c0 >= 0) ? ((c0 + 8) & ~7) : 0;
    int q1 = (c1 >= 0) ? ((c1 + 8) & ~7) : 0;
    s2[t] = q0 + q1;
    __syncthreads();
    for (int o = 1; o < 256; o <<= 1) {              // Hillis-Steele inclusive scan
        int v = (t >= o) ? s2[t - o] : 0;
        __syncthreads();
        s2[t] += v;
        __syncthreads();
    }
    int ex = s2[t] - (q0 + q1);                      // exclusive offset of node n0
    if (c0 >= 0) { int g = gbase + ex;      rp2[n0] = g; csr2[g] = n0; cur[2 * t]     = ex + 1; }
    if (c1 >= 0) { int g = gbase + ex + q0; rp2[n1] = g; csr2[g] = n1; cur[2 * t + 1] = ex + q0 + 1; }
    __syncthreads();
    int beg = bbase[b], end = bbase[b + 1];
    for (int j = beg + t; j < end; j += 256) {
        int pk = bkt[j];
        int pos = gbase + atomicAdd(&cur[pk >> 17], 1);
        csr2[pos] = pk & 0x1FFFF;
    }
    __syncthreads();
    if (c0 >= 0) { int e0 = ex + q0;      for (int j = cur[2 * t];     j < e0; ++j) csr2[gbase + j] = NN; }
    if (c1 >= 0) { int e1 = ex + q0 + q1; for (int j = cur[2 * t + 1]; j < e1; ++j) csr2[gbase + j] = NN; }
}

// ---------------- h2s = (in @ W) * dis[row] ----------------

__global__ __launch_bounds__(256) void k_gemm(const float* __restrict__ in,
                                              const float* __restrict__ W,
                                              const double* __restrict__ dis,
                                              float* __restrict__ h2s) {
    __shared__ float sW[DD * DD];        // 16 KB
    __shared__ float sIn[128 * 65];      // 33.3 KB
    int t = threadIdx.x;
    int brow = blockIdx.x * 128;
#pragma unroll
    for (int i = 0; i < 16; ++i) sW[t + 256 * i] = W[t + 256 * i];
#pragma unroll
    for (int i = 0; i < 32; ++i) {
        int idx = t + 256 * i;
        int rr = idx >> 6, kk = idx & 63;
        int gr = brow + rr; if (gr >= NN) gr = NN - 1;
        sIn[rr * 65 + kk] = in[(size_t)gr * DD + kk];
    }
    __syncthreads();
    int cg = t & 7;
    int rg = t >> 3;
    const float* sInB = &sIn[rg * 4 * 65];

    float aE[4][8], aO[4][8];
#pragma unroll
    for (int i = 0; i < 4; ++i)
#pragma unroll
        for (int j = 0; j < 8; ++j) { aE[i][j] = 0.f; aO[i][j] = 0.f; }

#pragma unroll 4
    for (int k = 0; k < DD; k += 2) {
        float4 w0 = *(const float4*)&sW[k * DD + cg * 8];
        float4 w1 = *(const float4*)&sW[k * DD + cg * 8 + 4];
        float4 w2 = *(const float4*)&sW[(k + 1) * DD + cg * 8];
        float4 w3 = *(const float4*)&sW[(k + 1) * DD + cg * 8 + 4];
        float wv0[8] = {w0.x, w0.y, w0.z, w0.w, w1.x, w1.y, w1.z, w1.w};
        float wv1[8] = {w2.x, w2.y, w2.z, w2.w, w3.x, w3.y, w3.z, w3.w};
#pragma unroll
        for (int i = 0; i < 4; ++i) {
            float a0 = sInB[i * 65 + k];
            float a1 = sInB[i * 65 + k + 1];
#pragma unroll
            for (int j = 0; j < 8; ++j) {
                aE[i][j] = fmaf(a0, wv0[j], aE[i][j]);
                aO[i][j] = fmaf(a1, wv1[j], aO[i][j]);
            }
        }
    }

#pragma unroll
    for (int i = 0; i < 4; ++i) {
        int row = brow + rg * 4 + i;
        if (row < NN) {
            double dr = dis[row];
            float o[8];
#pragma unroll
            for (int j = 0; j < 8; ++j)
                o[j] = (float)((double)(aE[i][j] + aO[i][j]) * dr);
            *(float4*)&h2s[(size_t)row * DD + cg * 8]     = make_float4(o[0], o[1], o[2], o[3]);
            *(float4*)&h2s[(size_t)row * DD + cg * 8 + 4] = make_float4(o[4], o[5], o[6], o[7]);
        }
    }
}

// ---------------- gather-aggregate: lane = feature, padded CSR ----------------

__global__ __launch_bounds__(256) void k_aggr(const int* __restrict__ rp2,
                                              const int* __restrict__ csr2,
                                              const float* __restrict__ h2s,
                                              const double* __restrict__ dis,
                                              const float* __restrict__ b,
                                              float* __restrict__ out,
                                              int apply_elu) {
    int gid = blockIdx.x * 256 + threadIdx.x;
    int node = gid >> 6;
    int lane = gid & 63;
    int beg = __builtin_amdgcn_readfirstlane(rp2[node]);
    int end = __builtin_amdgcn_readfirstlane(rp2[node + 1]);
    double a0 = 0.0, a1 = 0.0;
    for (int j = beg; j < end; j += 8) {
        int4 i0 = *(const int4*)&csr2[j];
        int4 i1 = *(const int4*)&csr2[j + 4];
        float v0 = h2s[(size_t)(unsigned)i0.x * DD + lane];
        float v1 = h2s[(size_t)(unsigned)i0.y * DD + lane];
        float v2 = h2s[(size_t)(unsigned)i0.z * DD + lane];
        float v3 = h2s[(size_t)(unsigned)i0.w * DD + lane];
        float v4 = h2s[(size_t)(unsigned)i1.x * DD + lane];
        float v5 = h2s[(size_t)(unsigned)i1.y * DD + lane];
        float v6 = h2s[(size_t)(unsigned)i1.z * DD + lane];
        float v7 = h2s[(size_t)(unsigned)i1.w * DD + lane];
        a0 += (double)v0; a1 += (double)v1;
        a0 += (double)v2; a1 += (double)v3;
        a0 += (double)v4; a1 += (double)v5;
        a0 += (double)v6; a1 += (double)v7;
    }
    float vf = (float)(dis[node] * (a0 + a1) + (double)b[lane]);
    if (apply_elu && vf <= 0.f) vf = expm1f(vf);
    out[gid] = vf;
}

// ---------------- launch ----------------

static inline size_t align256(size_t x) { return (x + 255) & ~(size_t)255; }

extern "C" void kernel_launch(void* const* d_in, const int* in_sizes, int n_in,
                              void* d_out, int out_size, void* d_ws, size_t ws_size,
                              hipStream_t stream) {
    const float* x  = (const float*)d_in[0];
    const int*   ei = (const int*)d_in[1];
    const float* W1 = (const float*)d_in[3];
    const float* b1 = (const float*)d_in[4];
    const float* W2 = (const float*)d_in[5];
    const float* b2 = (const float*)d_in[6];
    const float* W3 = (const float*)d_in[7];
    const float* b3 = (const float*)d_in[8];
    const float* W4 = (const float*)d_in[9];
    const float* b4 = (const float*)d_in[10];
    float* out = (float*)d_out;

    char* ws = (char*)d_ws;
    size_t off = 0;
    double* dis   = (double*)(ws + off); off = align256(off + (size_t)NN * sizeof(double));
    float*  h2s   = (float*) (ws + off); off = align256(off + (size_t)(NN + 1) * DD * sizeof(float));
    float*  A     = (float*) (ws + off); off = align256(off + (size_t)NN * DD * sizeof(float));
    int*    ncnt  = (int*)   (ws + off); off = align256(off + (size_t)NN * sizeof(int));
    int*    rp2   = (int*)   (ws + off); off = align256(off + (size_t)(NN + 1) * sizeof(int));
    int*    bcnt  = (int*)   (ws + off); off = align256(off + (size_t)(NBKT + 1) * sizeof(int));
    int*    bbase = (int*)   (ws + off); off = align256(off + (size_t)(NBKT + 1) * sizeof(int));
    int*    bcur  = (int*)   (ws + off); off = align256(off + (size_t)(NBKT + 1) * sizeof(int));
    int*    bptot = (int*)   (ws + off); off = align256(off + (size_t)(NBKT + 1) * sizeof(int));
    int*    pbase = (int*)   (ws + off); off = align256(off + (size_t)(NBKT + 1) * sizeof(int));
    int*    bkt   = (int*)   (ws + off); off = align256(off + (size_t)NE * sizeof(int));
    int*    csr2  = (int*)   (ws + off); off = align256(off + (size_t)CSR2_CAP * sizeof(int));

    hipMemsetAsync(bcnt, 0, (size_t)NBKT * sizeof(int), stream);
    hipMemsetAsync(h2s + (size_t)NN * DD, 0, DD * sizeof(float), stream);  // dummy row = 0

    k_bcount<<<NCH, 256, 0, stream>>>(ei, bcnt);
    k_bscan<<<1, 64, 0, stream>>>(bcnt, bbase, bcur);
    k_bscat<<<NCH, 256, 0, stream>>>(ei, bcur, bkt);
    k_ncnt<<<NBKT, 256, 0, stream>>>(bbase, bkt, ncnt, bptot, dis);
    k_pscan<<<1, 64, 0, stream>>>(bptot, pbase, rp2);
    k_bfill<<<NBKT, 256, 0, stream>>>(bbase, bkt, ncnt, pbase, rp2, csr2);

    struct Layer { const float* in; const float* b; const float* W; float* o; int elu; };
    Layer L[4] = {
        { x,   b1, W1, A,   1 },
        { A,   b2, W2, out, 1 },
        { out, b3, W3, A,   1 },
        { A,   b4, W4, out, 0 },
    };

    for (int l = 0; l < 4; ++l) {
        k_gemm<<<(NN + 127) / 128, 256, 0, stream>>>(L[l].in, L[l].W, dis, h2s);
        k_aggr<<<NN / 4, 256, 0, stream>>>(rp2, csr2, h2s, dis, L[l].b, L[l].o, L[l].elu);
    }
}

// Round 7
// 386.944 us; speedup vs baseline: 6.9893x; 1.0214x over previous
//
#include <hip/hip_runtime.h>

#define NN 100000
#define NE 1600000
#define DD 64
#define BSH 9
#define BSZ 512                      // nodes per bucket
#define NBKT 196                     // ceil(NN/BSZ)
#define CHUNK 8192                   // edges per scatter block
#define NCH ((NE + CHUNK - 1) / CHUNK)   // 196
#define CSR2_CAP (NE + 16 * (NBKT * BSZ))

// ---------------- P1: coarse bucket histogram ----------------

__global__ __launch_bounds__(256) void k_bcount(const int* __restrict__ ei,
                                                int* __restrict__ bcnt) {
    __shared__ int h[NBKT];
    int t = threadIdx.x;
    for (int i = t; i < NBKT; i += 256) h[i] = 0;
    __syncthreads();
    int base = blockIdx.x * CHUNK;
    for (int i = t; i < CHUNK; i += 256) {
        int e = base + i;
        if (e < NE) atomicAdd(&h[ei[NE + e] >> BSH], 1);
    }
    __syncthreads();
    for (int i = t; i < NBKT; i += 256)
        if (h[i]) atomicAdd(&bcnt[i], h[i]);
}

// ---------------- P1s: parallel scan of 196 bucket counts ----------------

__global__ __launch_bounds__(256) void k_bscan(const int* __restrict__ bcnt,
                                               int* __restrict__ bbase,
                                               int* __restrict__ bcur) {
    __shared__ int s[256];
    int t = threadIdx.x;
    int v = (t < NBKT) ? bcnt[t] : 0;
    s[t] = v;
    __syncthreads();
    for (int o = 1; o < 256; o <<= 1) {
        int x = (t >= o) ? s[t - o] : 0;
        __syncthreads();
        s[t] += x;
        __syncthreads();
    }
    int ex = s[t] - v;
    if (t < NBKT) { bbase[t] = ex; bcur[t] = ex; }
    if (t == NBKT) bbase[NBKT] = ex;     // total
}

// ---------------- P2: scatter edges into bucket-grouped packed lists ----------------
// packed = s | (dlocal << 17);  s < 2^17, dlocal < 512.

__global__ __launch_bounds__(256) void k_bscat(const int* __restrict__ ei,
                                               int* __restrict__ bcur,
                                               int* __restrict__ bkt) {
    __shared__ int h[NBKT], rbase[NBKT], rcur[NBKT];
    int t = threadIdx.x;
    for (int i = t; i < NBKT; i += 256) h[i] = 0;
    __syncthreads();
    int cb = blockIdx.x * CHUNK;
    int s[32], d[32];
#pragma unroll
    for (int i = 0; i < 32; ++i) {
        int e = cb + t + 256 * i;
        if (e < NE) {
            s[i] = ei[e];
            d[i] = ei[NE + e];
            atomicAdd(&h[d[i] >> BSH], 1);
        } else {
            d[i] = -1;
        }
    }
    __syncthreads();
    for (int i = t; i < NBKT; i += 256) {
        int c = h[i];
        rbase[i] = c ? atomicAdd(&bcur[i], c) : 0;
        rcur[i] = 0;
    }
    __syncthreads();
#pragma unroll
    for (int i = 0; i < 32; ++i) {
        if (d[i] >= 0) {
            int b = d[i] >> BSH;
            int pos = rbase[b] + atomicAdd(&rcur[b], 1);
            bkt[pos] = s[i] | ((d[i] & (BSZ - 1)) << 17);
        }
    }
}

// ---------------- P3a: per-bucket node counts (LDS), dis, padded totals ----------------
// padded row = ceil((deg+1)/16)*16

__global__ __launch_bounds__(256) void k_ncnt(const int* __restrict__ bbase,
                                              const int* __restrict__ bkt,
                                              int* __restrict__ ncnt,
                                              int* __restrict__ bptot,
                                              double* __restrict__ dis) {
    __shared__ int cnt[BSZ];
    __shared__ int red[256];
    int b = blockIdx.x, t = threadIdx.x;
    cnt[t] = 0; cnt[t + 256] = 0;
    __syncthreads();
    int beg = bbase[b], end = bbase[b + 1];
    for (int j = beg + t; j < end; j += 256)
        atomicAdd(&cnt[bkt[j] >> 17], 1);
    __syncthreads();
    int nb = b * BSZ;
    int n0 = nb + t, n1 = nb + t + 256;
    int c0 = cnt[t], c1 = cnt[t + 256];
    int p0 = (n0 < NN) ? ((c0 + 16) & ~15) : 0;
    int p1 = (n1 < NN) ? ((c1 + 16) & ~15) : 0;
    if (n0 < NN) { ncnt[n0] = c0; dis[n0] = 1.0 / sqrt((double)(c0 + 1)); }
    if (n1 < NN) { ncnt[n1] = c1; dis[n1] = 1.0 / sqrt((double)(c1 + 1)); }
    red[t] = p0 + p1;
    __syncthreads();
    for (int o = 128; o > 0; o >>= 1) {
        if (t < o) red[t] += red[t + o];
        __syncthreads();
    }
    if (t == 0) bptot[b] = red[0];
}

// ---------------- P3b: parallel scan of padded bucket totals ----------------

__global__ __launch_bounds__(256) void k_pscan(const int* __restrict__ bptot,
                                               int* __restrict__ pbase,
                                               int* __restrict__ rp2) {
    __shared__ int s[256];
    int t = threadIdx.x;
    int v = (t < NBKT) ? bptot[t] : 0;
    s[t] = v;
    __syncthreads();
    for (int o = 1; o < 256; o <<= 1) {
        int x = (t >= o) ? s[t - o] : 0;
        __syncthreads();
        s[t] += x;
        __syncthreads();
    }
    int ex = s[t] - v;
    if (t < NBKT) pbase[t] = ex;
    if (t == NBKT) rp2[NN] = ex;         // total padded entries
}

// ---------------- P3c: per-bucket rp2 + csr2 fill (LDS scan + LDS cursors) ----------------

__global__ __launch_bounds__(256) void k_bfill(const int* __restrict__ bbase,
                                               const int* __restrict__ bkt,
                                               const int* __restrict__ ncnt,
                                               const int* __restrict__ pbase,
                                               int* __restrict__ rp2,
                                               int* __restrict__ csr2) {
    __shared__ int cur[BSZ];
    __shared__ int s2[256];
    int b = blockIdx.x, t = threadIdx.x;
    int nb = b * BSZ;
    int gbase = pbase[b];
    int n0 = nb + 2 * t, n1 = nb + 2 * t + 1;
    int c0 = (n0 < NN) ? ncnt[n0] : -1;
    int c1 = (n1 < NN) ? ncnt[n1] : -1;
    int q0 = (c0 >= 0) ? ((c0 + 16) & ~15) : 0;
    int q1 = (c1 >= 0) ? ((c1 + 16) & ~15) : 0;
    s2[t] = q0 + q1;
    __syncthreads();
    for (int o = 1; o < 256; o <<= 1) {              // Hillis-Steele inclusive scan
        int v = (t >= o) ? s2[t - o] : 0;
        __syncthreads();
        s2[t] += v;
        __syncthreads();
    }
    int ex = s2[t] - (q0 + q1);                      // exclusive offset of node n0
    if (c0 >= 0) { int g = gbase + ex;      rp2[n0] = g; csr2[g] = n0; cur[2 * t]     = ex + 1; }
    if (c1 >= 0) { int g = gbase + ex + q0; rp2[n1] = g; csr2[g] = n1; cur[2 * t + 1] = ex + q0 + 1; }
    __syncthreads();
    int beg = bbase[b], end = bbase[b + 1];
    for (int j = beg + t; j < end; j += 256) {
        int pk = bkt[j];
        int pos = gbase + atomicAdd(&cur[pk >> 17], 1);
        csr2[pos] = pk & 0x1FFFF;
    }
    __syncthreads();
    if (c0 >= 0) { int e0 = ex + q0;      for (int j = cur[2 * t];     j < e0; ++j) csr2[gbase + j] = NN; }
    if (c1 >= 0) { int e1 = ex + q0 + q1; for (int j = cur[2 * t + 1]; j < e1; ++j) csr2[gbase + j] = NN; }
}

// ---------------- h2s = (in @ W) * dis[row] ----------------

__global__ __launch_bounds__(256) void k_gemm(const float* __restrict__ in,
                                              const float* __restrict__ W,
                                              const double* __restrict__ dis,
                                              float* __restrict__ h2s) {
    __shared__ float sW[DD * DD];        // 16 KB
    __shared__ float sIn[128 * 65];      // 33.3 KB
    int t = threadIdx.x;
    int brow = blockIdx.x * 128;
#pragma unroll
    for (int i = 0; i < 16; ++i) sW[t + 256 * i] = W[t + 256 * i];
#pragma unroll
    for (int i = 0; i < 32; ++i) {
        int idx = t + 256 * i;
        int rr = idx >> 6, kk = idx & 63;
        int gr = brow + rr; if (gr >= NN) gr = NN - 1;
        sIn[rr * 65 + kk] = in[(size_t)gr * DD + kk];
    }
    __syncthreads();
    int cg = t & 7;
    int rg = t >> 3;
    const float* sInB = &sIn[rg * 4 * 65];

    float aE[4][8], aO[4][8];
#pragma unroll
    for (int i = 0; i < 4; ++i)
#pragma unroll
        for (int j = 0; j < 8; ++j) { aE[i][j] = 0.f; aO[i][j] = 0.f; }

#pragma unroll 4
    for (int k = 0; k < DD; k += 2) {
        float4 w0 = *(const float4*)&sW[k * DD + cg * 8];
        float4 w1 = *(const float4*)&sW[k * DD + cg * 8 + 4];
        float4 w2 = *(const float4*)&sW[(k + 1) * DD + cg * 8];
        float4 w3 = *(const float4*)&sW[(k + 1) * DD + cg * 8 + 4];
        float wv0[8] = {w0.x, w0.y, w0.z, w0.w, w1.x, w1.y, w1.z, w1.w};
        float wv1[8] = {w2.x, w2.y, w2.z, w2.w, w3.x, w3.y, w3.z, w3.w};
#pragma unroll
        for (int i = 0; i < 4; ++i) {
            float a0 = sInB[i * 65 + k];
            float a1 = sInB[i * 65 + k + 1];
#pragma unroll
            for (int j = 0; j < 8; ++j) {
                aE[i][j] = fmaf(a0, wv0[j], aE[i][j]);
                aO[i][j] = fmaf(a1, wv1[j], aO[i][j]);
            }
        }
    }

#pragma unroll
    for (int i = 0; i < 4; ++i) {
        int row = brow + rg * 4 + i;
        if (row < NN) {
            double dr = dis[row];
            float o[8];
#pragma unroll
            for (int j = 0; j < 8; ++j)
                o[j] = (float)((double)(aE[i][j] + aO[i][j]) * dr);
            *(float4*)&h2s[(size_t)row * DD + cg * 8]     = make_float4(o[0], o[1], o[2], o[3]);
            *(float4*)&h2s[(size_t)row * DD + cg * 8 + 4] = make_float4(o[4], o[5], o[6], o[7]);
        }
    }
}

// ---------------- gather-aggregate: lane = feature, 16 gathers in flight ----------------

__global__ __launch_bounds__(256) void k_aggr(const int* __restrict__ rp2,
                                              const int* __restrict__ csr2,
                                              const float* __restrict__ h2s,
                                              const double* __restrict__ dis,
                                              const float* __restrict__ b,
                                              float* __restrict__ out,
                                              int apply_elu) {
    int gid = blockIdx.x * 256 + threadIdx.x;
    int node = gid >> 6;
    int lane = gid & 63;
    int beg = __builtin_amdgcn_readfirstlane(rp2[node]);
    int end = __builtin_amdgcn_readfirstlane(rp2[node + 1]);
    double a0 = 0.0, a1 = 0.0, a2 = 0.0, a3 = 0.0;
    for (int j = beg; j < end; j += 16) {
        int4 i0 = *(const int4*)&csr2[j];        // 64B-aligned, uniform -> s_load
        int4 i1 = *(const int4*)&csr2[j + 4];
        int4 i2 = *(const int4*)&csr2[j + 8];
        int4 i3 = *(const int4*)&csr2[j + 12];
        float v0  = h2s[(size_t)(unsigned)i0.x * DD + lane];
        float v1  = h2s[(size_t)(unsigned)i0.y * DD + lane];
        float v2  = h2s[(size_t)(unsigned)i0.z * DD + lane];
        float v3  = h2s[(size_t)(unsigned)i0.w * DD + lane];
        float v4  = h2s[(size_t)(unsigned)i1.x * DD + lane];
        float v5  = h2s[(size_t)(unsigned)i1.y * DD + lane];
        float v6  = h2s[(size_t)(unsigned)i1.z * DD + lane];
        float v7  = h2s[(size_t)(unsigned)i1.w * DD + lane];
        float v8  = h2s[(size_t)(unsigned)i2.x * DD + lane];
        float v9  = h2s[(size_t)(unsigned)i2.y * DD + lane];
        float v10 = h2s[(size_t)(unsigned)i2.z * DD + lane];
        float v11 = h2s[(size_t)(unsigned)i2.w * DD + lane];
        float v12 = h2s[(size_t)(unsigned)i3.x * DD + lane];
        float v13 = h2s[(size_t)(unsigned)i3.y * DD + lane];
        float v14 = h2s[(size_t)(unsigned)i3.z * DD + lane];
        float v15 = h2s[(size_t)(unsigned)i3.w * DD + lane];
        a0 += (double)v0;  a1 += (double)v1;  a2 += (double)v2;  a3 += (double)v3;
        a0 += (double)v4;  a1 += (double)v5;  a2 += (double)v6;  a3 += (double)v7;
        a0 += (double)v8;  a1 += (double)v9;  a2 += (double)v10; a3 += (double)v11;
        a0 += (double)v12; a1 += (double)v13; a2 += (double)v14; a3 += (double)v15;
    }
    double sum = (a0 + a1) + (a2 + a3);
    float vf = (float)(dis[node] * sum + (double)b[lane]);
    if (apply_elu && vf <= 0.f) vf = expm1f(vf);
    out[gid] = vf;
}

// ---------------- launch ----------------

static inline size_t align256(size_t x) { return (x + 255) & ~(size_t)255; }

extern "C" void kernel_launch(void* const* d_in, const int* in_sizes, int n_in,
                              void* d_out, int out_size, void* d_ws, size_t ws_size,
                              hipStream_t stream) {
    const float* x  = (const float*)d_in[0];
    const int*   ei = (const int*)d_in[1];
    const float* W1 = (const float*)d_in[3];
    const float* b1 = (const float*)d_in[4];
    const float* W2 = (const float*)d_in[5];
    const float* b2 = (const float*)d_in[6];
    const float* W3 = (const float*)d_in[7];
    const float* b3 = (const float*)d_in[8];
    const float* W4 = (const float*)d_in[9];
    const float* b4 = (const float*)d_in[10];
    float* out = (float*)d_out;

    char* ws = (char*)d_ws;
    size_t off = 0;
    double* dis   = (double*)(ws + off); off = align256(off + (size_t)NN * sizeof(double));
    float*  h2s   = (float*) (ws + off); off = align256(off + (size_t)(NN + 1) * DD * sizeof(float));
    float*  A     = (float*) (ws + off); off = align256(off + (size_t)NN * DD * sizeof(float));
    int*    ncnt  = (int*)   (ws + off); off = align256(off + (size_t)NN * sizeof(int));
    int*    rp2   = (int*)   (ws + off); off = align256(off + (size_t)(NN + 1) * sizeof(int));
    int*    bcnt  = (int*)   (ws + off); off = align256(off + (size_t)(NBKT + 1) * sizeof(int));
    int*    bbase = (int*)   (ws + off); off = align256(off + (size_t)(NBKT + 1) * sizeof(int));
    int*    bcur  = (int*)   (ws + off); off = align256(off + (size_t)(NBKT + 1) * sizeof(int));
    int*    bptot = (int*)   (ws + off); off = align256(off + (size_t)(NBKT + 1) * sizeof(int));
    int*    pbase = (int*)   (ws + off); off = align256(off + (size_t)(NBKT + 1) * sizeof(int));
    int*    bkt   = (int*)   (ws + off); off = align256(off + (size_t)NE * sizeof(int));
    int*    csr2  = (int*)   (ws + off); off = align256(off + (size_t)CSR2_CAP * sizeof(int));

    hipMemsetAsync(bcnt, 0, (size_t)NBKT * sizeof(int), stream);
    hipMemsetAsync(h2s + (size_t)NN * DD, 0, DD * sizeof(float), stream);  // dummy row = 0

    k_bcount<<<NCH, 256, 0, stream>>>(ei, bcnt);
    k_bscan<<<1, 256, 0, stream>>>(bcnt, bbase, bcur);
    k_bscat<<<NCH, 256, 0, stream>>>(ei, bcur, bkt);
    k_ncnt<<<NBKT, 256, 0, stream>>>(bbase, bkt, ncnt, bptot, dis);
    k_pscan<<<1, 256, 0, stream>>>(bptot, pbase, rp2);
    k_bfill<<<NBKT, 256, 0, stream>>>(bbase, bkt, ncnt, pbase, rp2, csr2);

    struct Layer { const float* in; const float* b; const float* W; float* o; int elu; };
    Layer L[4] = {
        { x,   b1, W1, A,   1 },
        { A,   b2, W2, out, 1 },
        { out, b3, W3, A,   1 },
        { A,   b4, W4, out, 0 },
    };

    for (int l = 0; l < 4; ++l) {
        k_gemm<<<(NN + 127) / 128, 256, 0, stream>>>(L[l].in, L[l].W, dis, h2s);
        k_aggr<<<NN / 4, 256, 0, stream>>>(rp2, csr2, h2s, dis, L[l].b, L[l].o, L[l].elu);
    }
}